// Round 1
// baseline (541.923 us; speedup 1.0000x reference)
//
#include <hip/hip_runtime.h>
#include <cstdint>
#include <cstddef>

// FullQKAttention: b=4, s=4096, d=64 (fp32)
//   out  = softmax(causal(mask(qk @ normalize(qk)^T * d^-1/2))) @ v
//   d_out = [ out (4*4096*64 floats) | attn (4*4096*4096 floats) ]
//
// Pipeline:
//   A) knorm:    rscale[b,j] = 0.125 / max(||qk[b,j]||, 1e-12)
//   B) attn_main: per (batch, paired i-tiles of 32 rows): sweep causal j-tiles
//      of 128; QK^T outer-product GEMM (fp32 VALU), exp (no max-pass needed:
//      logits bounded ~[-2,2]; diag handled exactly), write UNNORMALIZED p to
//      attn, accumulate rowsum + unnormalized PV; store out = PV/rowsum.
//   C) rescale:  attn lower-triangle *= 1/rowsum, upper triangle = 0.
//
// Workspace: needs 128 KB (rscale 64 KB + rsum 64 KB).

#define S_LEN 4096
#define D_DIM 64
#define N_B   4

// ---------------- kernel A: per-row normalization scale ----------------
__global__ __launch_bounds__(256) void knorm_kernel(const float* __restrict__ qk,
                                                    float* __restrict__ rscale) {
  const int row  = blockIdx.x * 4 + (threadIdx.x >> 6);
  const int lane = threadIdx.x & 63;
  float x = qk[(size_t)row * D_DIM + lane];
  float ss = x * x;
  #pragma unroll
  for (int m = 1; m < 64; m <<= 1) ss += __shfl_xor(ss, m, 64);
  if (lane == 0) {
    float n = fmaxf(sqrtf(ss), 1e-12f);
    rscale[row] = 0.125f / n;   // folds d^-1/2
  }
}

// ---------------- kernel B: fused QK^T + exp + PV ----------------
// 256 blocks (4 batches x 64 pair-slots), 256 threads.
// Thread map: rg = tid>>5 (row group, 4 rows each), cg = tid&31 (col group,
// 4 cols each for QK; (ec=cg&15, jp=cg>>4) for PV j-parity split).
__global__ __launch_bounds__(256, 1) void attn_main_kernel(
    const float* __restrict__ qk, const float* __restrict__ v,
    float* __restrict__ out, float* __restrict__ attn,
    const float* __restrict__ rscale, float* __restrict__ rsum_g) {

  // Qt/Kt/St layouts are transposed + XOR-chunk-swizzled:
  //   Qt[k][r]: float idx = k*32  + 4*((r>>2) ^ ((k>>2)&7)) + (r&3)
  //   Kt[k][j]: float idx = k*128 + 4*((j>>2) ^ ((k>>2)&7)) + (j&3)
  //   St[j][r]: float idx = j*36  + 4*((r>>2) ^ ((j>>2)&7)) + (r&3)
  // -> both the transpose-writes and the b128 fragment reads are bank-clean.
  __shared__ float Qt[64 * 32];
  __shared__ float Kt[64 * 128];
  __shared__ float Vl[128 * 64];   // linear, filled by global_load_lds
  __shared__ float St[128 * 36];
  __shared__ float Rs[128];

  const int tid  = threadIdx.x;
  const int rg   = tid >> 5;
  const int cg   = tid & 31;
  const int wave = tid >> 6;
  const int lane = tid & 63;
  const int ec   = cg & 15;
  const int jp   = cg >> 4;

  const int b    = blockIdx.x >> 6;
  const int slot = blockIdx.x & 63;

  const float* qb  = qk + (size_t)b * S_LEN * D_DIM;
  const float* vb0 = v  + (size_t)b * S_LEN * D_DIM;

  for (int half = 0; half < 2; ++half) {
    const int t  = half ? (127 - slot) : slot;   // paired i-tiles: uniform work
    const int i0 = t << 5;

    __syncthreads();   // previous tile's LDS consumers done

    // ---- stage Qt (register transpose, swizzled) ----
    #pragma unroll
    for (int it = 0; it < 2; ++it) {
      int idx = (it << 8) + tid;
      int kc = idx & 15, r = idx >> 4;
      float4 q4 = *(const float4*)&qb[(size_t)(i0 + r) * D_DIM + (kc << 2)];
      int sw = kc & 7;
      int base = (kc << 7) + (((r >> 2) ^ sw) << 2) + (r & 3);  // (4kc)*32 = kc<<7
      Qt[base]      = q4.x;
      Qt[base + 32] = q4.y;
      Qt[base + 64] = q4.z;
      Qt[base + 96] = q4.w;
    }

    float oacc[4][4];
    float rs_acc[4];
    #pragma unroll
    for (int m = 0; m < 4; ++m) {
      rs_acc[m] = 0.f;
      #pragma unroll
      for (int e = 0; e < 4; ++e) oacc[m][e] = 0.f;
    }

    const int ntiles = (i0 + 32 + 127) >> 7;

    for (int jt = 0; jt < ntiles; ++jt) {
      const int j0 = jt << 7;

      __syncthreads();   // prev-tile PV readers of Vl/St done before overwrite

      // ---- stage Kt (register transpose, swizzled) ----
      float4 kreg[8];
      #pragma unroll
      for (int it = 0; it < 8; ++it) {
        int idx = (it << 8) + tid;
        kreg[it] = *(const float4*)&qb[(size_t)(j0 + (idx >> 4)) * D_DIM + ((idx & 15) << 2)];
      }
      // ---- stage Vl (direct global->LDS, 16B/lane) ----
      const float* vb = vb0 + (size_t)j0 * D_DIM;
      #pragma unroll
      for (int it = 0; it < 8; ++it) {
        int seg = (it << 2) + wave;   // 32 segs x 1 KiB = 32 KiB
        __builtin_amdgcn_global_load_lds(
            (const __attribute__((address_space(1))) unsigned int*)(vb + (seg << 8)) + (lane << 2),
            (__attribute__((address_space(3))) unsigned int*)&Vl[seg << 8],
            16, 0, 0);
      }
      if (tid < 128) Rs[tid] = rscale[(size_t)b * S_LEN + j0 + tid];
      #pragma unroll
      for (int it = 0; it < 8; ++it) {
        int idx = (it << 8) + tid;
        int kc = idx & 15, j = idx >> 4;
        int sw = kc & 7;
        int base = (kc << 9) + ((((j >> 2) ^ sw)) << 2) + (j & 3);  // (4kc)*128 = kc<<9
        Kt[base]       = kreg[it].x;
        Kt[base + 128] = kreg[it].y;
        Kt[base + 256] = kreg[it].z;
        Kt[base + 384] = kreg[it].w;
      }

      __syncthreads();

      // ---- QK^T: acc[m][e] = sum_k Qt[k][4rg+m] * Kt[k][4cg+e] ----
      float acc[4][4];
      #pragma unroll
      for (int m = 0; m < 4; ++m)
        #pragma unroll
        for (int e = 0; e < 4; ++e) acc[m][e] = 0.f;

      #pragma unroll 4
      for (int k = 0; k < 64; ++k) {
        const int sk = (k >> 2) & 7;
        const float4 qa = *(const float4*)&Qt[(k << 5) + ((rg ^ sk) << 2)];
        const float4 kb = *(const float4*)&Kt[(k << 7) + ((cg ^ sk) << 2)];
        const float qv[4] = {qa.x, qa.y, qa.z, qa.w};
        const float kv[4] = {kb.x, kb.y, kb.z, kb.w};
        #pragma unroll
        for (int m = 0; m < 4; ++m)
          #pragma unroll
          for (int e = 0; e < 4; ++e)
            acc[m][e] = fmaf(qv[m], kv[e], acc[m][e]);
      }

      // ---- scale, mask, exp (no max-pass: logits bounded; diag exact) ----
      const float4 rq = *(const float4*)&Rs[cg << 2];
      const float rsv[4] = {rq.x, rq.y, rq.z, rq.w};
      float pp[4][4];
      const bool full = (j0 + 127) < i0;   // tile strictly below diagonal
      if (full) {
        #pragma unroll
        for (int m = 0; m < 4; ++m)
          #pragma unroll
          for (int e = 0; e < 4; ++e)
            pp[m][e] = __expf(acc[m][e] * rsv[e]);
      } else {
        #pragma unroll
        for (int m = 0; m < 4; ++m) {
          const int gi = i0 + (rg << 2) + m;
          #pragma unroll
          for (int e = 0; e < 4; ++e) {
            const int gj = j0 + (cg << 2) + e;
            float p = __expf(acc[m][e] * rsv[e]);
            if (gj > gi) p = 0.f;
            else if (gj == gi) p = (gi == 0) ? 1.f : 0.f;  // exp(-50000)->0; row0 -> 1
            pp[m][e] = p;
          }
        }
      }
      #pragma unroll
      for (int m = 0; m < 4; ++m)
        #pragma unroll
        for (int e = 0; e < 4; ++e)
          rs_acc[m] += pp[m][e];

      // ---- St write (swizzled) + attn tile write (unnormalized) ----
      #pragma unroll
      for (int e = 0; e < 4; ++e) {
        const int c = (cg << 2) + e;
        float4 w = make_float4(pp[0][e], pp[1][e], pp[2][e], pp[3][e]);
        *(float4*)&St[c * 36 + ((rg ^ (cg & 7)) << 2)] = w;
      }
      float* arow = attn + ((size_t)b * S_LEN + i0 + (rg << 2)) * (size_t)S_LEN + j0 + (cg << 2);
      #pragma unroll
      for (int m = 0; m < 4; ++m)
        *(float4*)(arow + (size_t)m * S_LEN) =
            make_float4(pp[m][0], pp[m][1], pp[m][2], pp[m][3]);

      __syncthreads();

      // ---- PV: oacc[m][e] += sum_{j%2==jp} St[j][4rg+m] * Vl[j][4ec+e] ----
      #pragma unroll 2
      for (int jj = 0; jj < 64; ++jj) {
        const int j = (jj << 1) | jp;
        const int sj = (j >> 2) & 7;
        const float4 pa = *(const float4*)&St[j * 36 + ((rg ^ sj) << 2)];
        const float4 vv = *(const float4*)&Vl[(j << 6) + (ec << 2)];
        const float pv[4]  = {pa.x, pa.y, pa.z, pa.w};
        const float vvv[4] = {vv.x, vv.y, vv.z, vv.w};
        #pragma unroll
        for (int m = 0; m < 4; ++m)
          #pragma unroll
          for (int e = 0; e < 4; ++e)
            oacc[m][e] = fmaf(pv[m], vvv[e], oacc[m][e]);
      }
    }  // j-tile loop

    // ---- row sums: all-reduce across the 32 lanes sharing rg ----
    float rtot[4], rinv[4];
    #pragma unroll
    for (int m = 0; m < 4; ++m) {
      float x = rs_acc[m];
      #pragma unroll
      for (int msk = 1; msk < 32; msk <<= 1) x += __shfl_xor(x, msk, 32);
      rtot[m] = x;
      rinv[m] = 1.0f / x;
    }
    if (cg == 0) {
      #pragma unroll
      for (int m = 0; m < 4; ++m)
        rsum_g[(size_t)b * S_LEN + i0 + (rg << 2) + m] = rtot[m];
    }

    // ---- merge jp halves of oacc, normalize, store out ----
    #pragma unroll
    for (int m = 0; m < 4; ++m) {
      #pragma unroll
      for (int e = 0; e < 4; ++e)
        oacc[m][e] += __shfl_xor(oacc[m][e], 16, 32);
      if (jp == 0) {
        float4 w = make_float4(oacc[m][0] * rinv[m], oacc[m][1] * rinv[m],
                               oacc[m][2] * rinv[m], oacc[m][3] * rinv[m]);
        *(float4*)&out[((size_t)b * S_LEN + i0 + (rg << 2) + m) * D_DIM + (ec << 2)] = w;
      }
    }
  }  // half
}

// ---------------- kernel C: normalize lower triangle, zero upper ----------------
__global__ __launch_bounds__(256) void rescale_kernel(float* __restrict__ attn,
                                                      const float* __restrict__ rsum_g) {
  const int tid = threadIdx.x;
  for (int rr = 0; rr < 8; ++rr) {
    const int gr = (blockIdx.x << 3) + rr;
    const int i  = gr & (S_LEN - 1);
    const float rinv = 1.0f / rsum_g[gr];
    float4* row = (float4*)(attn + ((size_t)gr << 12));
    // chunks written by kernel B for this row's i-tile (128-col granularity)
    const int wch = (((i | 31) + 128) >> 7) << 5;
    for (int c = tid; c < wch; c += 256) {
      float4 x = row[c];
      x.x *= rinv; x.y *= rinv; x.z *= rinv; x.w *= rinv;
      row[c] = x;
    }
    for (int c = wch + tid; c < 1024; c += 256)
      row[c] = make_float4(0.f, 0.f, 0.f, 0.f);
  }
}

extern "C" void kernel_launch(void* const* d_in, const int* in_sizes, int n_in,
                              void* d_out, int out_size, void* d_ws, size_t ws_size,
                              hipStream_t stream) {
  const float* qk = (const float*)d_in[0];
  const float* v  = (const float*)d_in[1];
  float* out  = (float*)d_out;
  float* attn = (float*)d_out + (size_t)N_B * S_LEN * D_DIM;

  float* rscale = (float*)d_ws;                       // 16384 floats
  float* rsum   = rscale + (size_t)N_B * S_LEN;       // 16384 floats (ws >= 128 KB)

  knorm_kernel<<<dim3(N_B * S_LEN / 4), dim3(256), 0, stream>>>(qk, rscale);
  attn_main_kernel<<<dim3(256), dim3(256), 0, stream>>>(qk, v, out, attn, rscale, rsum);
  rescale_kernel<<<dim3(N_B * S_LEN / 8), dim3(256), 0, stream>>>(attn, rsum);
}

// Round 2
// 434.616 us; speedup vs baseline: 1.2469x; 1.2469x over previous
//
#include <hip/hip_runtime.h>
#include <cstdint>
#include <cstddef>

// FullQKAttention (b=4, s=4096, d=64 fp32):
//   out = softmax(causal(q @ normalize(qk)^T * d^-1/2)) @ v ; also output attn.
// Round 2 structure:
//   knorm:      rscale[b,j] = 0.125 / max(||qk[b,j]||, eps)
//   attn_fused: per (batch, paired 32-row i-tiles):
//     sweep1: j-tiles of 128: stage K as bf16 hi/lo (XOR-swizzled LDS) + V fp32
//             (global_load_lds); QK^T via mfma_f32_16x16x32_bf16 x3 (hi/lo);
//             exp (logits bounded, no max pass; diag exact); accumulate rowsum;
//             PV via fp32 VALU 4x4 outer product (St/Vl as before).
//     finalize: cross-wave rowsum reduce -> rinv; store out = PV * rinv.
//     sweep2: recompute QK^T+exp, store attn = p * rinv (normalized, once);
//             zero-fill columns beyond the causal tile range.
// No rescale kernel; attn written exactly once (272 MB total writes).

#define S_LEN 4096
#define D_DIM 64
#define N_B   4
#define JT    128

typedef __bf16 bf16x8 __attribute__((ext_vector_type(8)));
typedef float  f32x4  __attribute__((ext_vector_type(4)));

// ---------------- kernel A: per-row normalization scale ----------------
__global__ __launch_bounds__(256) void knorm_kernel(const float* __restrict__ qk,
                                                    float* __restrict__ rscale) {
  const int row  = blockIdx.x * 4 + (threadIdx.x >> 6);
  const int lane = threadIdx.x & 63;
  float x = qk[(size_t)row * D_DIM + lane];
  float ss = x * x;
  #pragma unroll
  for (int m = 1; m < 64; m <<= 1) ss += __shfl_xor(ss, m, 64);
  if (lane == 0) {
    float n = fmaxf(sqrtf(ss), 1e-12f);
    rscale[row] = 0.125f / n;   // folds d^-1/2
  }
}

// K-LDS swizzle: element index for (row j, k-elem): 16B-granule XOR keeps
// both the staging writes (8B) and the b128 fragment reads bank-clean.
__device__ __forceinline__ int kidx(int j, int k) {
  return j * 64 + (k ^ ((j & 7) << 3));
}

// ---------------- fused attention kernel ----------------
__global__ __launch_bounds__(256, 1) void attn_fused(
    const float* __restrict__ qk, const float* __restrict__ v,
    float* __restrict__ out, float* __restrict__ attn,
    const float* __restrict__ rscale) {

  __shared__ __bf16 Khi[JT * 64];
  __shared__ __bf16 Klo[JT * 64];
  __shared__ float  Vl[JT * 64];      // linear (global_load_lds)
  __shared__ float  St[JT * 36];      // p tile [j][i], i<32 (+pad)
  __shared__ float  Rs[JT];
  __shared__ float  Rsum[4][32];
  __shared__ float  Rinv[32];

  const int tid = threadIdx.x;
  const int w   = tid >> 6;          // wave 0..3
  const int l   = tid & 63;
  const int lr  = l & 15;            // MFMA lane row/col
  const int lq  = l >> 4;            // MFMA lane quarter
  const int rg  = tid >> 5;          // PV row-group (4 rows)
  const int cg  = tid & 31;
  const int ec  = cg & 15;           // PV e-group (4 cols)
  const int jp  = cg >> 4;           // PV j-parity

  // XCD clustering: blk%8 = XCD -> batch fixed per XCD (K/V L2-resident)
  const int b    = blockIdx.x & 3;
  const int slot = ((blockIdx.x >> 3) << 1) | ((blockIdx.x >> 2) & 1); // 0..63

  const float* qb  = qk + (size_t)b * S_LEN * D_DIM;
  const float* vb0 = v  + (size_t)b * S_LEN * D_DIM;
  const float* rsb = rscale + (size_t)b * S_LEN;
  float* attb = attn + (size_t)b * S_LEN * S_LEN;

  for (int half = 0; half < 2; ++half) {
    const int t  = half ? (127 - slot) : slot;   // paired tiles: uniform work
    const int i0 = t << 5;
    const int n1 = (i0 + 32 + JT - 1) >> 7;      // causal j-tile count

    // ---- A-frags (Q) hi/lo, registers; lane: row lr, k-chunk lq*8 ----
    bf16x8 Ahi[2][2], Alo[2][2];
    #pragma unroll
    for (int f = 0; f < 2; ++f)
      #pragma unroll
      for (int ks = 0; ks < 2; ++ks) {
        const float* ap = qb + (size_t)(i0 + (f << 4) + lr) * D_DIM + ks * 32 + lq * 8;
        float4 x0 = *(const float4*)ap;
        float4 x1 = *(const float4*)(ap + 4);
        float xs[8] = {x0.x, x0.y, x0.z, x0.w, x1.x, x1.y, x1.z, x1.w};
        #pragma unroll
        for (int e = 0; e < 8; ++e) {
          __bf16 h = (__bf16)xs[e];
          Ahi[f][ks][e] = h;
          Alo[f][ks][e] = (__bf16)(xs[e] - (float)h);
        }
      }

    float rs_acc[8];
    float oacc[4][4];
    #pragma unroll
    for (int m = 0; m < 8; ++m) rs_acc[m] = 0.f;
    #pragma unroll
    for (int m = 0; m < 4; ++m)
      #pragma unroll
      for (int e = 0; e < 4; ++e) oacc[m][e] = 0.f;

    // =================== sweep 1: rowsum + PV ===================
    for (int jt = 0; jt < n1; ++jt) {
      const int j0 = jt << 7;
      __syncthreads();   // prev tile LDS consumers done

      // V: direct global->LDS (32 KB)
      const float* vb = vb0 + (size_t)j0 * D_DIM;
      #pragma unroll
      for (int it = 0; it < 8; ++it) {
        int seg = (it << 2) + w;
        __builtin_amdgcn_global_load_lds(
            (const __attribute__((address_space(1))) unsigned int*)(vb + (seg << 8)) + (l << 2),
            (__attribute__((address_space(3))) unsigned int*)&Vl[seg << 8],
            16, 0, 0);
      }
      if (tid < JT) Rs[tid] = rsb[j0 + tid];
      // K: fp32 -> bf16 hi/lo, swizzled
      #pragma unroll
      for (int it = 0; it < 8; ++it) {
        int idx = (it << 8) + tid;
        int kq = idx & 15, j = idx >> 4;
        float4 x = *(const float4*)&qb[(size_t)(j0 + j) * D_DIM + (kq << 2)];
        float xv[4] = {x.x, x.y, x.z, x.w};
        union { __bf16 bb[4]; uint2 u; } hu, lu;
        #pragma unroll
        for (int c = 0; c < 4; ++c) {
          __bf16 h = (__bf16)xv[c];
          hu.bb[c] = h;
          lu.bb[c] = (__bf16)(xv[c] - (float)h);
        }
        int ki = kidx(j, kq << 2);
        *(uint2*)&Khi[ki] = hu.u;
        *(uint2*)&Klo[ki] = lu.u;
      }
      __syncthreads();

      // ---- QK^T: mfma bf16 x3 ----
      f32x4 acc[2][2];
      #pragma unroll
      for (int f = 0; f < 2; ++f)
        #pragma unroll
        for (int jf = 0; jf < 2; ++jf) acc[f][jf] = (f32x4){0.f, 0.f, 0.f, 0.f};
      #pragma unroll
      for (int ks = 0; ks < 2; ++ks) {
        bf16x8 Bh[2], Bl[2];
        #pragma unroll
        for (int jf = 0; jf < 2; ++jf) {
          int j = (w << 5) + (jf << 4) + lr;
          int ki = kidx(j, ks * 32 + lq * 8);
          Bh[jf] = *(const bf16x8*)&Khi[ki];
          Bl[jf] = *(const bf16x8*)&Klo[ki];
        }
        #pragma unroll
        for (int f = 0; f < 2; ++f)
          #pragma unroll
          for (int jf = 0; jf < 2; ++jf) {
            acc[f][jf] = __builtin_amdgcn_mfma_f32_16x16x32_bf16(Ahi[f][ks], Bh[jf], acc[f][jf], 0, 0, 0);
            acc[f][jf] = __builtin_amdgcn_mfma_f32_16x16x32_bf16(Ahi[f][ks], Bl[jf], acc[f][jf], 0, 0, 0);
            acc[f][jf] = __builtin_amdgcn_mfma_f32_16x16x32_bf16(Alo[f][ks], Bh[jf], acc[f][jf], 0, 0, 0);
          }
      }

      // ---- scale/mask/exp -> St + rowsum ----
      #pragma unroll
      for (int jf = 0; jf < 2; ++jf) {
        const int jl  = (w << 5) + (jf << 4) + lr;
        const float rsj = Rs[jl];
        const int jg  = j0 + jl;
        #pragma unroll
        for (int f = 0; f < 2; ++f)
          #pragma unroll
          for (int r = 0; r < 4; ++r) {
            const int il = (f << 4) + (lq << 2) + r;
            const int ig = i0 + il;
            float p = __expf(acc[f][jf][r] * rsj);
            if (jg > ig) p = 0.f;
            else if (jg == ig) p = (ig == 0) ? 1.f : 0.f;
            rs_acc[(f << 2) + r] += p;
            St[jl * 36 + il] = p;
          }
      }
      __syncthreads();

      // ---- PV (fp32 VALU 4x4, j-parity split) ----
      #pragma unroll 2
      for (int jj = 0; jj < 64; ++jj) {
        const int j = (jj << 1) | jp;
        const float4 pa = *(const float4*)&St[j * 36 + (rg << 2)];
        const float4 vv = *(const float4*)&Vl[(j << 6) + (ec << 2)];
        const float pv[4]  = {pa.x, pa.y, pa.z, pa.w};
        const float vvv[4] = {vv.x, vv.y, vv.z, vv.w};
        #pragma unroll
        for (int m = 0; m < 4; ++m)
          #pragma unroll
          for (int e = 0; e < 4; ++e)
            oacc[m][e] = fmaf(pv[m], vvv[e], oacc[m][e]);
      }
    }

    // =================== finalize: rowsum -> rinv, out ===================
    #pragma unroll
    for (int u = 0; u < 8; ++u) {
      float x = rs_acc[u];
      #pragma unroll
      for (int msk = 1; msk < 16; msk <<= 1) x += __shfl_xor(x, msk, 64);
      rs_acc[u] = x;
    }
    if (lr == 0) {
      #pragma unroll
      for (int f = 0; f < 2; ++f)
        #pragma unroll
        for (int r = 0; r < 4; ++r)
          Rsum[w][(f << 4) + (lq << 2) + r] = rs_acc[(f << 2) + r];
    }
    __syncthreads();
    if (tid < 32) {
      float s = Rsum[0][tid] + Rsum[1][tid] + Rsum[2][tid] + Rsum[3][tid];
      Rinv[tid] = 1.0f / s;
    }
    __syncthreads();

    // out = PV * rinv  (merge jp halves)
    #pragma unroll
    for (int m = 0; m < 4; ++m) {
      const float rinv_m = Rinv[(rg << 2) + m];
      #pragma unroll
      for (int e = 0; e < 4; ++e)
        oacc[m][e] += __shfl_xor(oacc[m][e], 16, 32);
      if (jp == 0) {
        float4 wv = make_float4(oacc[m][0] * rinv_m, oacc[m][1] * rinv_m,
                                oacc[m][2] * rinv_m, oacc[m][3] * rinv_m);
        *(float4*)&out[((size_t)b * S_LEN + i0 + (rg << 2) + m) * D_DIM + (ec << 2)] = wv;
      }
    }

    // rinv regs for sweep2 (rows this lane owns in MFMA layout)
    float rinv_r[8];
    #pragma unroll
    for (int f = 0; f < 2; ++f)
      #pragma unroll
      for (int r = 0; r < 4; ++r)
        rinv_r[(f << 2) + r] = Rinv[(f << 4) + (lq << 2) + r];

    // =================== sweep 2: write normalized attn ===================
    for (int jt = 0; jt < n1; ++jt) {
      const int j0 = jt << 7;
      __syncthreads();
      if (tid < JT) Rs[tid] = rsb[j0 + tid];
      #pragma unroll
      for (int it = 0; it < 8; ++it) {
        int idx = (it << 8) + tid;
        int kq = idx & 15, j = idx >> 4;
        float4 x = *(const float4*)&qb[(size_t)(j0 + j) * D_DIM + (kq << 2)];
        float xv[4] = {x.x, x.y, x.z, x.w};
        union { __bf16 bb[4]; uint2 u; } hu, lu;
        #pragma unroll
        for (int c = 0; c < 4; ++c) {
          __bf16 h = (__bf16)xv[c];
          hu.bb[c] = h;
          lu.bb[c] = (__bf16)(xv[c] - (float)h);
        }
        int ki = kidx(j, kq << 2);
        *(uint2*)&Khi[ki] = hu.u;
        *(uint2*)&Klo[ki] = lu.u;
      }
      __syncthreads();

      f32x4 acc[2][2];
      #pragma unroll
      for (int f = 0; f < 2; ++f)
        #pragma unroll
        for (int jf = 0; jf < 2; ++jf) acc[f][jf] = (f32x4){0.f, 0.f, 0.f, 0.f};
      #pragma unroll
      for (int ks = 0; ks < 2; ++ks) {
        bf16x8 Bh[2], Bl[2];
        #pragma unroll
        for (int jf = 0; jf < 2; ++jf) {
          int j = (w << 5) + (jf << 4) + lr;
          int ki = kidx(j, ks * 32 + lq * 8);
          Bh[jf] = *(const bf16x8*)&Khi[ki];
          Bl[jf] = *(const bf16x8*)&Klo[ki];
        }
        #pragma unroll
        for (int f = 0; f < 2; ++f)
          #pragma unroll
          for (int jf = 0; jf < 2; ++jf) {
            acc[f][jf] = __builtin_amdgcn_mfma_f32_16x16x32_bf16(Ahi[f][ks], Bh[jf], acc[f][jf], 0, 0, 0);
            acc[f][jf] = __builtin_amdgcn_mfma_f32_16x16x32_bf16(Ahi[f][ks], Bl[jf], acc[f][jf], 0, 0, 0);
            acc[f][jf] = __builtin_amdgcn_mfma_f32_16x16x32_bf16(Alo[f][ks], Bh[jf], acc[f][jf], 0, 0, 0);
          }
      }

      #pragma unroll
      for (int jf = 0; jf < 2; ++jf) {
        const int jl  = (w << 5) + (jf << 4) + lr;
        const float rsj = Rs[jl];
        const int jg  = j0 + jl;
        #pragma unroll
        for (int f = 0; f < 2; ++f)
          #pragma unroll
          for (int r = 0; r < 4; ++r) {
            const int il = (f << 4) + (lq << 2) + r;
            const int ig = i0 + il;
            float p = __expf(acc[f][jf][r] * rsj);
            if (jg > ig) p = 0.f;
            else if (jg == ig) p = (ig == 0) ? 1.f : 0.f;
            attb[(size_t)(i0 + il) * S_LEN + jg] = p * rinv_r[(f << 2) + r];
          }
      }
    }

    // zero-fill columns beyond the causal tile range
    {
      const int c0 = n1 << 5;   // first untouched float4 column
      const float4 z4 = make_float4(0.f, 0.f, 0.f, 0.f);
      #pragma unroll
      for (int rr = 0; rr < 8; ++rr) {
        float4* dst = (float4*)(attb + (size_t)(i0 + (w << 3) + rr) * S_LEN);
        for (int c = c0 + l; c < 1024; c += 64) dst[c] = z4;
      }
    }
  }
}

extern "C" void kernel_launch(void* const* d_in, const int* in_sizes, int n_in,
                              void* d_out, int out_size, void* d_ws, size_t ws_size,
                              hipStream_t stream) {
  const float* qk = (const float*)d_in[0];
  const float* v  = (const float*)d_in[1];
  float* out  = (float*)d_out;
  float* attn = (float*)d_out + (size_t)N_B * S_LEN * D_DIM;
  float* rscale = (float*)d_ws;   // 16384 floats

  knorm_kernel<<<dim3(N_B * S_LEN / 4), dim3(256), 0, stream>>>(qk, rscale);
  attn_fused<<<dim3(256), dim3(256), 0, stream>>>(qk, v, out, attn, rscale);
}

// Round 3
// 387.019 us; speedup vs baseline: 1.4002x; 1.1230x over previous
//
#include <hip/hip_runtime.h>
#include <cstdint>
#include <cstddef>

// FullQKAttention (b=4, s=4096, d=64 fp32):
//   out = softmax(causal(q @ normalize(qk)^T * d^-1/2)) @ v ; also output attn.
// R3: swapped-operand MFMA everywhere (QK^T as mfma(K,Q) -> D[j,i]), PV via
// MFMA with in-register shfl-gathered A (zero-padded K), bf16 hi/lo splits for
// fp32 accuracy, 512-thr blocks, double-buffered K/V^T staging (T14 split),
// one barrier per j-tile. Sweep2 recomputes QK^T and writes normalized attn
// as float4; upper triangle zero-filled in-kernel.

#define S_LEN 4096
#define D_DIM 64
#define N_B   4

typedef __bf16 bf16x8 __attribute__((ext_vector_type(8)));
typedef float  f32x4  __attribute__((ext_vector_type(4)));

__device__ __forceinline__ unsigned pk2(float a, float b) {
  union { __bf16 h[2]; unsigned u; } t;
  t.h[0] = (__bf16)a; t.h[1] = (__bf16)b;
  return t.u;
}
__device__ __forceinline__ float rlo(float x) { return x - (float)(__bf16)x; }

// K LDS layout [j][k] bf16, 16B-granule XOR swizzle (conflict-floor b128 reads)
__device__ __forceinline__ int kidx(int j, int k) {
  return j * 64 + (k ^ ((j & 7) << 3));
}
// V^T LDS layout [e][j] bf16, granule-8 XOR swizzle on j by (e&15)
__device__ __forceinline__ int vtidx(int e, int j) {
  return e * 128 + ((((j >> 3) ^ (e & 15))) << 3) + (j & 7);
}

// ---------------- kernel A: per-row normalization scale ----------------
__global__ __launch_bounds__(256) void knorm_kernel(const float* __restrict__ qk,
                                                    float* __restrict__ rscale) {
  const int row  = blockIdx.x * 4 + (threadIdx.x >> 6);
  const int lane = threadIdx.x & 63;
  float x = qk[(size_t)row * D_DIM + lane];
  float ss = x * x;
  #pragma unroll
  for (int m = 1; m < 64; m <<= 1) ss += __shfl_xor(ss, m, 64);
  if (lane == 0) {
    float n = fmaxf(sqrtf(ss), 1e-12f);
    rscale[row] = 0.125f / n;   // folds d^-1/2
  }
}

__device__ __forceinline__ void loadK(const float* __restrict__ qb, int j0,
                                      int sj, int skq, float4 kr[4]) {
  #pragma unroll
  for (int it = 0; it < 4; ++it)
    kr[it] = *(const float4*)&qb[(size_t)(j0 + it*32 + sj) * D_DIM + skq*4];
}
__device__ __forceinline__ void writeK(unsigned short* Khi, unsigned short* Klo,
                                       int sj, int skq, const float4 kr[4]) {
  #pragma unroll
  for (int it = 0; it < 4; ++it) {
    int ki = kidx(it*32 + sj, skq*4);
    uint2 H = make_uint2(pk2(kr[it].x, kr[it].y), pk2(kr[it].z, kr[it].w));
    uint2 L = make_uint2(pk2(rlo(kr[it].x), rlo(kr[it].y)),
                         pk2(rlo(kr[it].z), rlo(kr[it].w)));
    *(uint2*)&Khi[ki] = H;
    *(uint2*)&Klo[ki] = L;
  }
}
__device__ __forceinline__ void loadV(const float* __restrict__ vb0, int j0,
                                      int w, int ve, float vr[4][4]) {
  #pragma unroll
  for (int git = 0; git < 4; ++git) {
    int j4 = git*32 + w*4;
    #pragma unroll
    for (int r = 0; r < 4; ++r)
      vr[git][r] = vb0[(size_t)(j0 + j4 + r) * D_DIM + ve];
  }
}
__device__ __forceinline__ void writeV(unsigned short* VThi, unsigned short* VTlo,
                                       int w, int ve, const float vr[4][4]) {
  #pragma unroll
  for (int git = 0; git < 4; ++git) {
    int j4 = git*32 + w*4;
    int vi = vtidx(ve, j4);
    uint2 H = make_uint2(pk2(vr[git][0], vr[git][1]), pk2(vr[git][2], vr[git][3]));
    uint2 L = make_uint2(pk2(rlo(vr[git][0]), rlo(vr[git][1])),
                         pk2(rlo(vr[git][2]), rlo(vr[git][3])));
    *(uint2*)&VThi[vi] = H;
    *(uint2*)&VTlo[vi] = L;
  }
}

// QK^T (swapped): aq[f] = K_tile(j=w*16+lr rows) . Q(f-th 16 i-cols), bf16 x3
__device__ __forceinline__ void qkmm(const unsigned short* Khi,
                                     const unsigned short* Klo,
                                     const bf16x8 Qh[2][2], const bf16x8 Ql[2][2],
                                     int lr, int lq, int w, f32x4 aq[2]) {
  aq[0] = (f32x4){0.f, 0.f, 0.f, 0.f};
  aq[1] = (f32x4){0.f, 0.f, 0.f, 0.f};
  #pragma unroll
  for (int ks = 0; ks < 2; ++ks) {
    int ki = kidx(w*16 + lr, ks*32 + lq*8);
    bf16x8 Ah = *(const bf16x8*)&Khi[ki];
    bf16x8 Al = *(const bf16x8*)&Klo[ki];
    #pragma unroll
    for (int f = 0; f < 2; ++f) {
      aq[f] = __builtin_amdgcn_mfma_f32_16x16x32_bf16(Ah, Qh[f][ks], aq[f], 0, 0, 0);
      aq[f] = __builtin_amdgcn_mfma_f32_16x16x32_bf16(Ah, Ql[f][ks], aq[f], 0, 0, 0);
      aq[f] = __builtin_amdgcn_mfma_f32_16x16x32_bf16(Al, Qh[f][ks], aq[f], 0, 0, 0);
    }
  }
}

// ---------------- fused attention kernel ----------------
__global__ __launch_bounds__(512, 2) void attn_fused(
    const float* __restrict__ qk, const float* __restrict__ v,
    float* __restrict__ out, float* __restrict__ attn,
    const float* __restrict__ rscale) {

  __shared__ __align__(16) unsigned char smem[2][65536];
  __shared__ float Rsum[8][32];
  __shared__ float Rinv[32];

  const int tid = threadIdx.x;
  const int w   = tid >> 6;
  const int l   = tid & 63;
  const int lr  = l & 15;
  const int lq  = l >> 4;
  const int skq = tid & 15;   // K-stage: dim quad
  const int sj  = tid >> 4;   // K-stage: j base
  const int ve  = tid & 63;   // V-stage: e column

  const int b    = blockIdx.x & 3;
  const int slot = blockIdx.x >> 2;     // 0..63

  const float* qb  = qk + (size_t)b * S_LEN * D_DIM;
  const float* vb0 = v  + (size_t)b * S_LEN * D_DIM;
  const float* rsb = rscale + (size_t)b * S_LEN;
  float* attb = attn + (size_t)b * S_LEN * S_LEN;

  // PV shfl-gather lane constants (A-frag k=lq*8..+8, real only for lq<2)
  const int s0  = (((lq << 1)    ) & 3) * 16 + lr;
  const int s1  = (((lq << 1) | 1) & 3) * 16 + lr;
  const bool vld = (lq < 2);

  for (int half = 0; half < 2; ++half) {
    const int t0 = half ? (127 - slot) : slot;   // paired tiles: uniform work
    const int i0 = t0 << 5;
    const int n1 = (i0 + 32 + 127) >> 7;

    // ---- Q fragments hi/lo (B-operand: col i = lr, k-chunk lq*8) ----
    bf16x8 Qh[2][2], Ql[2][2];
    #pragma unroll
    for (int f = 0; f < 2; ++f)
      #pragma unroll
      for (int ks = 0; ks < 2; ++ks) {
        const float* ap = qb + (size_t)(i0 + f*16 + lr) * D_DIM + ks*32 + lq*8;
        float4 x0 = *(const float4*)ap;
        float4 x1 = *(const float4*)(ap + 4);
        union { unsigned u[4]; bf16x8 v; } H, L;
        H.u[0] = pk2(x0.x, x0.y); H.u[1] = pk2(x0.z, x0.w);
        H.u[2] = pk2(x1.x, x1.y); H.u[3] = pk2(x1.z, x1.w);
        L.u[0] = pk2(rlo(x0.x), rlo(x0.y)); L.u[1] = pk2(rlo(x0.z), rlo(x0.w));
        L.u[2] = pk2(rlo(x1.x), rlo(x1.y)); L.u[3] = pk2(rlo(x1.z), rlo(x1.w));
        Qh[f][ks] = H.v; Ql[f][ks] = L.v;
      }

    f32x4 pvacc[2][4];
    #pragma unroll
    for (int f = 0; f < 2; ++f)
      #pragma unroll
      for (int ef = 0; ef < 4; ++ef) pvacc[f][ef] = (f32x4){0.f, 0.f, 0.f, 0.f};
    float rs_acc[2] = {0.f, 0.f};

    // =================== sweep 1: rowsum + PV ===================
    int cur = 0;
    float4 kr[4]; float vr[4][4]; float4 rs_cur, rs_next;
    loadK(qb, 0, sj, skq, kr);
    loadV(vb0, 0, w, ve, vr);
    rs_cur = *(const float4*)&rsb[w*16 + lq*4];
    {
      unsigned short* Khi = (unsigned short*)smem[0];
      writeK(Khi, Khi + 8192, sj, skq, kr);
      writeV(Khi + 16384, Khi + 24576, w, ve, vr);
    }
    __syncthreads();

    for (int jt = 0; jt < n1; ++jt) {
      const int j0 = jt << 7;
      const bool more = (jt + 1 < n1);
      if (more) {
        loadK(qb, j0 + 128, sj, skq, kr);
        loadV(vb0, j0 + 128, w, ve, vr);
        rs_next = *(const float4*)&rsb[j0 + 128 + w*16 + lq*4];
      }
      const unsigned short* Khi  = (const unsigned short*)smem[cur];
      const unsigned short* Klo  = Khi + 8192;
      const unsigned short* VThi = Khi + 16384;
      const unsigned short* VTlo = Khi + 24576;

      f32x4 aq[2];
      qkmm(Khi, Klo, Qh, Ql, lr, lq, w, aq);

      // exp / mask / pack (logits bounded: no max pass; diag exact)
      unsigned pwh[2][2], pwl[2][2];
      const float rsa[4] = {rs_cur.x, rs_cur.y, rs_cur.z, rs_cur.w};
      #pragma unroll
      for (int f = 0; f < 2; ++f) {
        const int ig = i0 + f*16 + lr;
        float p[4];
        #pragma unroll
        for (int r = 0; r < 4; ++r) {
          const int jg = j0 + w*16 + lq*4 + r;
          float pp = __expf(aq[f][r] * rsa[r]);
          if (jg > ig) pp = 0.f;
          else if (jg == ig) pp = (ig == 0) ? 1.f : 0.f;
          p[r] = pp;
        }
        rs_acc[f] += (p[0] + p[1]) + (p[2] + p[3]);
        pwh[f][0] = pk2(p[0], p[1]);           pwh[f][1] = pk2(p[2], p[3]);
        pwl[f][0] = pk2(rlo(p[0]), rlo(p[1])); pwl[f][1] = pk2(rlo(p[2]), rlo(p[3]));
      }

      // PV: B-frags from V^T LDS (dup j for lq>=2; their A is zero)
      bf16x8 Bh[4], Bl[4];
      #pragma unroll
      for (int ef = 0; ef < 4; ++ef) {
        int vi = vtidx(ef*16 + lr, w*16 + (lq & 1)*8);
        Bh[ef] = *(const bf16x8*)&VThi[vi];
        Bl[ef] = *(const bf16x8*)&VTlo[vi];
      }
      #pragma unroll
      for (int f = 0; f < 2; ++f) {
        union { unsigned u[4]; bf16x8 v; } AH, AL;
        unsigned h0 = __shfl(pwh[f][0], s0, 64), h1 = __shfl(pwh[f][1], s0, 64);
        unsigned h2 = __shfl(pwh[f][0], s1, 64), h3 = __shfl(pwh[f][1], s1, 64);
        unsigned g0 = __shfl(pwl[f][0], s0, 64), g1 = __shfl(pwl[f][1], s0, 64);
        unsigned g2 = __shfl(pwl[f][0], s1, 64), g3 = __shfl(pwl[f][1], s1, 64);
        AH.u[0] = vld ? h0 : 0u; AH.u[1] = vld ? h1 : 0u;
        AH.u[2] = vld ? h2 : 0u; AH.u[3] = vld ? h3 : 0u;
        AL.u[0] = vld ? g0 : 0u; AL.u[1] = vld ? g1 : 0u;
        AL.u[2] = vld ? g2 : 0u; AL.u[3] = vld ? g3 : 0u;
        #pragma unroll
        for (int ef = 0; ef < 4; ++ef) {
          pvacc[f][ef] = __builtin_amdgcn_mfma_f32_16x16x32_bf16(AH.v, Bh[ef], pvacc[f][ef], 0, 0, 0);
          pvacc[f][ef] = __builtin_amdgcn_mfma_f32_16x16x32_bf16(AH.v, Bl[ef], pvacc[f][ef], 0, 0, 0);
          pvacc[f][ef] = __builtin_amdgcn_mfma_f32_16x16x32_bf16(AL.v, Bh[ef], pvacc[f][ef], 0, 0, 0);
        }
      }

      if (more) {
        unsigned short* nKhi = (unsigned short*)smem[cur ^ 1];
        writeK(nKhi, nKhi + 8192, sj, skq, kr);
        writeV(nKhi + 16384, nKhi + 24576, w, ve, vr);
        rs_cur = rs_next;
      }
      __syncthreads();
      if (more) cur ^= 1;
    }

    // =================== finalize: rowsum -> rinv, out ===================
    #pragma unroll
    for (int f = 0; f < 2; ++f) {
      float x = rs_acc[f];
      x += __shfl_xor(x, 16, 64);
      x += __shfl_xor(x, 32, 64);
      rs_acc[f] = x;
    }
    if (l < 16) { Rsum[w][l] = rs_acc[0]; Rsum[w][16 + l] = rs_acc[1]; }
    float* Red = (float*)smem[0];   // 64 KB, aliases buffer 0 (compute done)
    #pragma unroll
    for (int f = 0; f < 2; ++f)
      #pragma unroll
      for (int ef = 0; ef < 4; ++ef)
        #pragma unroll
        for (int r = 0; r < 4; ++r)
          Red[w*2048 + (f*16 + lq*4 + r)*64 + ef*16 + lr] = pvacc[f][ef][r];
    __syncthreads();
    if (tid < 32) {
      float s = 0.f;
      #pragma unroll
      for (int ww = 0; ww < 8; ++ww) s += Rsum[ww][tid];
      Rinv[tid] = 1.0f / s;
    }
    __syncthreads();
    {
      const int iloc = tid >> 4, e4 = (tid & 15) << 2;
      f32x4 s = (f32x4){0.f, 0.f, 0.f, 0.f};
      #pragma unroll
      for (int ww = 0; ww < 8; ++ww)
        s += *(const f32x4*)&Red[ww*2048 + iloc*64 + e4];
      const float ri = Rinv[iloc];
      float4 o = make_float4(s[0]*ri, s[1]*ri, s[2]*ri, s[3]*ri);
      *(float4*)&out[((size_t)b * S_LEN + i0 + iloc) * D_DIM + e4] = o;
    }
    const float rinv_reg[2] = { Rinv[lr], Rinv[16 + lr] };
    __syncthreads();   // Red reads done before sweep-2 staging

    // =================== sweep 2: write normalized attn ===================
    cur = 0;
    loadK(qb, 0, sj, skq, kr);
    rs_cur = *(const float4*)&rsb[w*16 + lq*4];
    {
      unsigned short* Khi = (unsigned short*)smem[0];
      writeK(Khi, Khi + 8192, sj, skq, kr);
    }
    __syncthreads();

    for (int jt = 0; jt < n1; ++jt) {
      const int j0 = jt << 7;
      const bool more = (jt + 1 < n1);
      if (more) {
        loadK(qb, j0 + 128, sj, skq, kr);
        rs_next = *(const float4*)&rsb[j0 + 128 + w*16 + lq*4];
      }
      const unsigned short* Khi = (const unsigned short*)smem[cur];
      const unsigned short* Klo = Khi + 8192;

      f32x4 aq[2];
      qkmm(Khi, Klo, Qh, Ql, lr, lq, w, aq);

      const float rsa[4] = {rs_cur.x, rs_cur.y, rs_cur.z, rs_cur.w};
      #pragma unroll
      for (int f = 0; f < 2; ++f) {
        const int ig = i0 + f*16 + lr;
        float4 st;
        float* stp = (float*)&st;
        #pragma unroll
        for (int r = 0; r < 4; ++r) {
          const int jg = j0 + w*16 + lq*4 + r;
          float pp = __expf(aq[f][r] * rsa[r]);
          if (jg > ig) pp = 0.f;
          else if (jg == ig) pp = (ig == 0) ? 1.f : 0.f;
          stp[r] = pp * rinv_reg[f];
        }
        *(float4*)&attb[(size_t)ig * S_LEN + j0 + w*16 + lq*4] = st;
      }

      if (more) {
        unsigned short* nKhi = (unsigned short*)smem[cur ^ 1];
        writeK(nKhi, nKhi + 8192, sj, skq, kr);
        rs_cur = rs_next;
      }
      __syncthreads();
      if (more) cur ^= 1;
    }

    // zero-fill columns beyond the causal tile range
    {
      const int c0 = n1 << 5;   // first untouched float4 column
      const float4 z = make_float4(0.f, 0.f, 0.f, 0.f);
      #pragma unroll
      for (int rr = 0; rr < 4; ++rr) {
        float4* dst = (float4*)(attb + (size_t)(i0 + w*4 + rr) * S_LEN);
        for (int c = c0 + l; c < 1024; c += 64) dst[c] = z;
      }
    }
  }  // half
}

extern "C" void kernel_launch(void* const* d_in, const int* in_sizes, int n_in,
                              void* d_out, int out_size, void* d_ws, size_t ws_size,
                              hipStream_t stream) {
  const float* qk = (const float*)d_in[0];
  const float* v  = (const float*)d_in[1];
  float* out  = (float*)d_out;
  float* attn = (float*)d_out + (size_t)N_B * S_LEN * D_DIM;
  float* rscale = (float*)d_ws;   // 16384 floats

  knorm_kernel<<<dim3(N_B * S_LEN / 4), dim3(256), 0, stream>>>(qk, rscale);
  attn_fused<<<dim3(256), dim3(512), 0, stream>>>(qk, v, out, attn, rscale);
}